// Round 5
// baseline (4764.292 us; speedup 1.0000x reference)
//
#include <hip/hip_runtime.h>
#include <math.h>

typedef unsigned long long u64;
typedef unsigned int u32;

// Problem constants
#define KC 8192     // num_embeddings
#define DD 512      // embedding_dim
#define BB 32768    // batch
// Pass1 tiling
#define NSPLIT 4
#define BM 128
#define BN 128
#define BDs 32
#define KRANGE (KC / NSPLIT)   // 2048
#define NT (KRANGE / BN)       // 16
#define LDSTR (BM + 4)         // padded LDS row stride (floats)
#define TOPS 4                 // candidates kept per (row, split)

// ---------------- workspace layout (bytes) ----------------
#define WS_SEG   0ull                                   // f32 [KC*DD] segment sum (zeroed)
#define WS_CNT   (WS_SEG + (size_t)KC * DD * 4)         // f32 [KC] counts (zeroed)
#define WS_LOSS  (WS_CNT + (size_t)KC * 4)              // f64 [1] loss accum (zeroed)
#define WS_W2    (WS_LOSS + 8)                          // f32 [KC] ||w||^2 (numpy-exact)
#define WS_ZZ    (WS_W2 + (size_t)KC * 4)               // f32 [BB] ||z||^2 (numpy-exact)
#define WS_TI    (WS_ZZ + (size_t)BB * 4)               // i32 [NSPLIT][BB][TOPS]
#define WS_CSN   (WS_TI + (size_t)NSPLIT * BB * TOPS * 4) // f32 [KC] cs_norm
#define ZERO_BYTES (WS_LOSS + 8)

// ---------------- output layout (f32 elements) ----------------
#define OQ  0ull                        // quantized_st [BB*DD]
#define OI  ((size_t)BB * DD)           // indices as float [BB]
#define OS  (OI + BB)                   // commitment, codebook, vq, perplexity [4]
#define ONC (OS + 4)                    // new_ema_cluster_size [KC]
#define ONS (ONC + KC)                  // new_ema_embedding_sum [KC*DD]
#define OCB (ONS + (size_t)KC * DD)     // new_codebook [KC*DD]

__device__ __forceinline__ u64 sortable_pack(float e, int col) {
    u32 s = __float_as_uint(e);
    s = (s & 0x80000000u) ? ~s : (s | 0x80000000u);
    return ((u64)s << 32) | (u32)col;
}
__device__ __forceinline__ u64 umin64(u64 a, u64 b) { return a < b ? a : b; }
__device__ __forceinline__ u64 umax64(u64 a, u64 b) { return a > b ? a : b; }

// numpy-exact pairwise f32 sum of squares per row (n=512: 256+256 -> 4x base-128
// with 8 accumulators, fixed combine tree). __fmul_rn/__fadd_rn block contraction.
__global__ __launch_bounds__(256)
void np_sqnorm_kernel(const float* __restrict__ in, float* __restrict__ out, int rows) {
    int r = blockIdx.x * 256 + threadIdx.x;
    if (r >= rows) return;
    const float* p = in + (size_t)r * DD;
    float Bv[4];
#pragma unroll
    for (int blk = 0; blk < 4; blk++) {
        const float4* p4 = (const float4*)(p + blk * 128);
        float4 a = p4[0], b = p4[1];
        float a0 = __fmul_rn(a.x, a.x), a1 = __fmul_rn(a.y, a.y);
        float a2 = __fmul_rn(a.z, a.z), a3 = __fmul_rn(a.w, a.w);
        float a4 = __fmul_rn(b.x, b.x), a5 = __fmul_rn(b.y, b.y);
        float a6 = __fmul_rn(b.z, b.z), a7 = __fmul_rn(b.w, b.w);
#pragma unroll
        for (int t = 1; t < 16; t++) {
            a = p4[2 * t]; b = p4[2 * t + 1];
            a0 = __fadd_rn(a0, __fmul_rn(a.x, a.x)); a1 = __fadd_rn(a1, __fmul_rn(a.y, a.y));
            a2 = __fadd_rn(a2, __fmul_rn(a.z, a.z)); a3 = __fadd_rn(a3, __fmul_rn(a.w, a.w));
            a4 = __fadd_rn(a4, __fmul_rn(b.x, b.x)); a5 = __fadd_rn(a5, __fmul_rn(b.y, b.y));
            a6 = __fadd_rn(a6, __fmul_rn(b.z, b.z)); a7 = __fadd_rn(a7, __fmul_rn(b.w, b.w));
        }
        Bv[blk] = __fadd_rn(__fadd_rn(__fadd_rn(a0, a1), __fadd_rn(a2, a3)),
                            __fadd_rn(__fadd_rn(a4, a5), __fadd_rn(a6, a7)));
    }
    out[r] = __fadd_rn(__fadd_rn(Bv[0], Bv[1]), __fadd_rn(Bv[2], Bv[3]));
}

// Fused f32 GEMM (z . W^T) + per-row top-3/thread -> top-4/split shortlist by
// fine score w2[k] - 2*dot (zz omitted: constant per row). Ties -> lowest index
// via sortable u64 packing.
__global__ __launch_bounds__(256)
void pass1_kernel(const float* __restrict__ Z, const float* __restrict__ W,
                  const float* __restrict__ w2, int* __restrict__ ti) {
    __shared__ u64 smem64[4224];          // 33792 B; staging floats + merge u64s
    float* zs = (float*)smem64;
    float* wsm = (float*)smem64 + BDs * LDSTR;

    int bx = blockIdx.x;
    int sp = bx & (NSPLIT - 1);
    int rb = bx >> 2;
    int row0 = rb * BM, col0 = sp * KRANGE;
    int tid = threadIdx.x, tx = tid & 15, ty = tid >> 4;

    u64 K3[8][3];
#pragma unroll
    for (int i = 0; i < 8; i++) { K3[i][0] = ~0ull; K3[i][1] = ~0ull; K3[i][2] = ~0ull; }

    for (int nt = 0; nt < NT; ++nt) {
        int kc0 = col0 + nt * BN;
        float acc[8][8];
#pragma unroll
        for (int i = 0; i < 8; i++)
#pragma unroll
            for (int j = 0; j < 8; j++) acc[i][j] = 0.0f;

        for (int d0 = 0; d0 < DD; d0 += BDs) {
            __syncthreads();
#pragma unroll
            for (int l = 0; l < 4; l++) {
                int f = tid + l * 256;
                int r = f >> 3, c4 = f & 7;
                float4 v = *(const float4*)(Z + (size_t)(row0 + r) * DD + d0 + c4 * 4);
                int db = c4 * 4;
                zs[(db + 0) * LDSTR + r] = v.x;
                zs[(db + 1) * LDSTR + r] = v.y;
                zs[(db + 2) * LDSTR + r] = v.z;
                zs[(db + 3) * LDSTR + r] = v.w;
            }
#pragma unroll
            for (int l = 0; l < 4; l++) {
                int f = tid + l * 256;
                int r = f >> 3, c4 = f & 7;
                float4 v = *(const float4*)(W + (size_t)(kc0 + r) * DD + d0 + c4 * 4);
                int db = c4 * 4;
                wsm[(db + 0) * LDSTR + r] = v.x;
                wsm[(db + 1) * LDSTR + r] = v.y;
                wsm[(db + 2) * LDSTR + r] = v.z;
                wsm[(db + 3) * LDSTR + r] = v.w;
            }
            __syncthreads();
#pragma unroll 4
            for (int d = 0; d < BDs; ++d) {
                float4 za = *(const float4*)&zs[d * LDSTR + ty * 8];
                float4 zb = *(const float4*)&zs[d * LDSTR + ty * 8 + 4];
                float4 wa = *(const float4*)&wsm[d * LDSTR + tx * 8];
                float4 wb = *(const float4*)&wsm[d * LDSTR + tx * 8 + 4];
                float zr[8] = {za.x, za.y, za.z, za.w, zb.x, zb.y, zb.z, zb.w};
                float wr[8] = {wa.x, wa.y, wa.z, wa.w, wb.x, wb.y, wb.z, wb.w};
#pragma unroll
                for (int i = 0; i < 8; i++)
#pragma unroll
                    for (int j = 0; j < 8; j++)
                        acc[i][j] = fmaf(zr[i], wr[j], acc[i][j]);
            }
        }
        // epilogue: top-3 insert per row (sorted u64s; (score,idx) lex order)
#pragma unroll
        for (int j = 0; j < 8; j++) {
            int col = kc0 + tx * 8 + j;
            float w2c = w2[col];
#pragma unroll
            for (int i = 0; i < 8; i++) {
                float e = fmaf(-2.0f, acc[i][j], w2c);
                u64 x = sortable_pack(e, col);
                if (x < K3[i][2]) {
                    u64 t1 = umax64(K3[i][0], x); K3[i][0] = umin64(K3[i][0], x);
                    u64 t2 = umax64(K3[i][1], t1); K3[i][1] = umin64(K3[i][1], t1);
                    K3[i][2] = umin64(K3[i][2], t2);
                }
            }
        }
    }

    // two-phase merge: 64 rows per phase, 16 threads x 3 entries -> top-4/row
    u64* mb = smem64;   // [64][49] u64 = 25088 B
    for (int ph = 0; ph < 2; ph++) {
        __syncthreads();
#pragma unroll
        for (int i = 0; i < 8; i++) {
            int r = ty * 8 + i;
            if ((r >> 6) == ph) {
                int rl = r & 63;
                mb[rl * 49 + 3 * tx + 0] = K3[i][0];
                mb[rl * 49 + 3 * tx + 1] = K3[i][1];
                mb[rl * 49 + 3 * tx + 2] = K3[i][2];
            }
        }
        __syncthreads();
        if (tid < 64) {
            u64 k0 = ~0ull, k1 = ~0ull, k2 = ~0ull, k3 = ~0ull;
            for (int e2 = 0; e2 < 48; e2++) {
                u64 x = mb[tid * 49 + e2];
                if (x < k3) {
                    u64 t1 = umax64(k0, x); k0 = umin64(k0, x);
                    u64 t2 = umax64(k1, t1); k1 = umin64(k1, t1);
                    u64 t3 = umax64(k2, t2); k2 = umin64(k2, t2);
                    k3 = umin64(k3, t3);
                }
            }
            int r = ph * 64 + tid;
            size_t o = ((size_t)sp * BB + row0 + r) * TOPS;
            ti[o + 0] = (int)(u32)k0;
            ti[o + 1] = (int)(u32)k1;
            ti[o + 2] = (int)(u32)k2;
            ti[o + 3] = (int)(u32)k3;
        }
    }
}

// One wave per row: emulate the reference f32 distance chain over 16 candidates.
// dist = fl32( fl32( zz - 2*fl32(dot_f64) ) + w2 ), argmin with lowest-index ties.
__global__ __launch_bounds__(256)
void rerank_kernel(const float* __restrict__ Z, const float* __restrict__ W,
                   const int* __restrict__ ti, const float* __restrict__ zzv,
                   const float* __restrict__ w2,
                   float* __restrict__ outq, float* __restrict__ outi,
                   float* __restrict__ counts, float* __restrict__ seg,
                   double* __restrict__ loss_acc) {
    int row = (blockIdx.x * blockDim.x + threadIdx.x) >> 6;
    int lane = threadIdx.x & 63;
    if (row >= BB) return;
    const float* zp = Z + (size_t)row * DD;
    float zf[8];
#pragma unroll
    for (int j = 0; j < 8; j++) zf[j] = zp[lane + j * 64];
    float zz = zzv[row];

    u64 best = ~0ull;
    for (int c = 0; c < NSPLIT * TOPS; c++) {
        int ix = ti[((size_t)(c >> 2) * BB + row) * TOPS + (c & 3)];
        const float* wp = W + (size_t)ix * DD;
        double dot = 0.0;
#pragma unroll
        for (int j = 0; j < 8; j++)
            dot = fma((double)zf[j], (double)wp[lane + j * 64], dot);
#pragma unroll
        for (int o = 32; o; o >>= 1) dot += __shfl_down(dot, o, 64);
        float E = (float)dot;
        E = __shfl(E, 0, 64);
        float dist = __fadd_rn(__fadd_rn(zz, __fmul_rn(-2.0f, E)), w2[ix]);
        u64 x = sortable_pack(dist, ix);
        best = umin64(best, x);
    }
    int besti = (int)(u32)best;

    if (!lane) { outi[row] = (float)besti; atomicAdd(&counts[besti], 1.0f); }
    const float* wp = W + (size_t)besti * DD;
    double ls = 0.0;
#pragma unroll
    for (int j = 0; j < 8; j++) {
        float q = wp[lane + j * 64];
        // quantized_st = fl(z + fl(q - z)) to match the reference bit pattern
        outq[(size_t)row * DD + lane + j * 64] = __fadd_rn(zf[j], __fsub_rn(q, zf[j]));
        float d = __fsub_rn(zf[j], q);
        ls = fma((double)d, (double)d, ls);
        atomicAdd(&seg[(size_t)besti * DD + lane + j * 64], zf[j]);
    }
#pragma unroll
    for (int o = 32; o; o >>= 1) ls += __shfl_down(ls, o, 64);
    if (!lane) atomicAdd(loss_acc, ls);
}

// single block: new_ema_cluster_size, n, cs_norm, losses, perplexity
__global__ void finalize_kernel(const float* __restrict__ ema_cs,
                                const float* __restrict__ counts,
                                const double* __restrict__ loss_acc,
                                float* __restrict__ out_ncs,
                                float* __restrict__ out_scal,
                                float* __restrict__ csnorm) {
    __shared__ double sn[256], sh[256];
    int tid = threadIdx.x;
    double nl = 0.0, hl = 0.0;
    for (int k = tid; k < KC; k += 256) {
        float c = counts[k];
        float ncs = 0.99f * ema_cs[k] + 0.01f * c;
        out_ncs[k] = ncs;
        nl += (double)ncs;
        double p = (double)c * (1.0 / (double)BB);
        hl += p * log(p + 1e-10);
    }
    sn[tid] = nl; sh[tid] = hl; __syncthreads();
    for (int s = 128; s; s >>= 1) {
        if (tid < s) { sn[tid] += sn[tid + s]; sh[tid] += sh[tid + s]; }
        __syncthreads();
    }
    if (!tid) {
        double L = loss_acc[0] * (1.0 / ((double)BB * DD));
        out_scal[0] = (float)L;              // commitment_loss
        out_scal[1] = (float)L;              // codebook_loss (same value)
        out_scal[2] = (float)(L + 0.25 * L); // vq_loss
        out_scal[3] = (float)exp(-sh[0]);    // perplexity
    }
    double n = sn[0];
    for (int k = tid; k < KC; k += 256) {
        double ncs = (double)out_ncs[k];
        csnorm[k] = (float)((ncs + 1e-5) / (n + (double)KC * 1e-5) * n);
    }
}

// elementwise: new_ema_embedding_sum and new_codebook
__global__ __launch_bounds__(256)
void ema_kernel(const float* __restrict__ ema_sum, const float* __restrict__ seg,
                const float* __restrict__ csnorm,
                float* __restrict__ out_ns, float* __restrict__ out_cb) {
    int i = blockIdx.x * 256 + threadIdx.x;
    if (i >= KC * DD / 4) return;
    int k = i >> 7;   // DD/4 = 128 float4 per row
    float4 es = ((const float4*)ema_sum)[i];
    float4 sg = ((const float4*)seg)[i];
    float4 ns;
    ns.x = 0.99f * es.x + 0.01f * sg.x;
    ns.y = 0.99f * es.y + 0.01f * sg.y;
    ns.z = 0.99f * es.z + 0.01f * sg.z;
    ns.w = 0.99f * es.w + 0.01f * sg.w;
    ((float4*)out_ns)[i] = ns;
    float cn = csnorm[k];
    float4 cb; cb.x = ns.x / cn; cb.y = ns.y / cn; cb.z = ns.z / cn; cb.w = ns.w / cn;
    ((float4*)out_cb)[i] = cb;
}

extern "C" void kernel_launch(void* const* d_in, const int* in_sizes, int n_in,
                              void* d_out, int out_size, void* d_ws, size_t ws_size,
                              hipStream_t stream) {
    (void)in_sizes; (void)n_in; (void)out_size; (void)ws_size;
    const float* Z       = (const float*)d_in[0];
    const float* W       = (const float*)d_in[1];
    const float* ema_cs  = (const float*)d_in[2];
    const float* ema_sum = (const float*)d_in[3];
    float* out = (float*)d_out;
    char* ws = (char*)d_ws;

    float*  seg  = (float*)(ws + WS_SEG);
    float*  cnt  = (float*)(ws + WS_CNT);
    double* loss = (double*)(ws + WS_LOSS);
    float*  w2   = (float*)(ws + WS_W2);
    float*  zz   = (float*)(ws + WS_ZZ);
    int*    ti   = (int*)(ws + WS_TI);
    float*  csn  = (float*)(ws + WS_CSN);

    hipMemsetAsync(ws, 0, ZERO_BYTES, stream);   // seg + counts + loss
    np_sqnorm_kernel<<<KC / 256, 256, 0, stream>>>(W, w2, KC);
    np_sqnorm_kernel<<<BB / 256, 256, 0, stream>>>(Z, zz, BB);
    pass1_kernel<<<(BB / BM) * NSPLIT, 256, 0, stream>>>(Z, W, w2, ti);
    rerank_kernel<<<BB / 4, 256, 0, stream>>>(Z, W, ti, zz, w2, out + OQ, out + OI, cnt, seg, loss);
    finalize_kernel<<<1, 256, 0, stream>>>(ema_cs, cnt, loss, out + ONC, out + OS, csn);
    ema_kernel<<<KC * DD / 4 / 256, 256, 0, stream>>>(ema_sum, seg, csn, out + ONS, out + OCB);
}

// Round 6
// 1607.426 us; speedup vs baseline: 2.9639x; 2.9639x over previous
//
#include <hip/hip_runtime.h>
#include <math.h>

typedef unsigned long long u64;
typedef unsigned int u32;
typedef unsigned short u16;
typedef __attribute__((ext_vector_type(8))) short bf16x8;
typedef __attribute__((ext_vector_type(8))) u16  u16x8;
typedef __attribute__((ext_vector_type(4))) float f32x4;

// Problem constants
#define KC 8192     // num_embeddings
#define DD 512      // embedding_dim
#define BB 32768    // batch
// Pass1 tiling
#define NSPLIT 4
#define KRANGE (KC / NSPLIT)   // 2048
#define BMM 128                // row tile
#define BNN 128                // col tile
#define NCT (KRANGE / BNN)     // 16 col-tiles per split
#define TOPS 4                 // candidates kept per (row, split)

// ---------------- workspace layout (bytes) ----------------
#define WS_SEG   0ull                                     // f32 [KC*DD] segment sum (zeroed)
#define WS_CNT   (WS_SEG + (size_t)KC * DD * 4)           // f32 [KC] counts (zeroed)
#define WS_LOSS  (WS_CNT + (size_t)KC * 4)                // f64 [1] loss accum (zeroed)
#define WS_W2    (WS_LOSS + 8)                            // f32 [KC] ||w||^2 (numpy-exact)
#define WS_ZZ    (WS_W2 + (size_t)KC * 4)                 // f32 [BB] ||z||^2 (numpy-exact)
#define WS_TI    (WS_ZZ + (size_t)BB * 4)                 // i32 [NSPLIT][BB][TOPS]
#define WS_CSN   (WS_TI + (size_t)NSPLIT * BB * TOPS * 4) // f32 [KC] cs_norm
#define WS_WB    (WS_CSN + (size_t)KC * 4)                // u16 [KC*DD] bf16 codebook
#define ZERO_BYTES (WS_LOSS + 8)

// ---------------- output layout (f32 elements) ----------------
#define OQ  0ull                        // quantized_st [BB*DD]
#define OI  ((size_t)BB * DD)           // indices as float [BB]
#define OS  (OI + BB)                   // commitment, codebook, vq, perplexity [4]
#define ONC (OS + 4)                    // new_ema_cluster_size [KC]
#define ONS (ONC + KC)                  // new_ema_embedding_sum [KC*DD]
#define OCB (ONS + (size_t)KC * DD)     // new_codebook [KC*DD]

__device__ __forceinline__ u64 sortable_pack(float e, int col) {
    u32 s = __float_as_uint(e);
    s = (s & 0x80000000u) ? ~s : (s | 0x80000000u);
    return ((u64)s << 32) | (u32)col;
}
__device__ __forceinline__ u64 umin64(u64 a, u64 b) { return a < b ? a : b; }
__device__ __forceinline__ u64 umax64(u64 a, u64 b) { return a > b ? a : b; }
__device__ __forceinline__ u16 f2bf(float f) {   // RNE f32 -> bf16
    u32 u = __float_as_uint(f);
    u32 r = u + 0x7FFFu + ((u >> 16) & 1u);
    return (u16)(r >> 16);
}

// f32 -> bf16 bulk convert, 8 elements/thread
__global__ __launch_bounds__(256)
void cvt_kernel(const float* __restrict__ in, u16* __restrict__ out, int n8) {
    int i = blockIdx.x * 256 + threadIdx.x;
    if (i >= n8) return;
    float4 a = ((const float4*)in)[2 * i];
    float4 b = ((const float4*)in)[2 * i + 1];
    u16x8 r = { f2bf(a.x), f2bf(a.y), f2bf(a.z), f2bf(a.w),
                f2bf(b.x), f2bf(b.y), f2bf(b.z), f2bf(b.w) };
    ((u16x8*)out)[i] = r;
}

// numpy-exact pairwise f32 sum of squares per row (n=512: 256+256 -> 4x base-128
// with 8 accumulators, fixed combine tree). __fmul_rn/__fadd_rn block contraction.
__global__ __launch_bounds__(256)
void np_sqnorm_kernel(const float* __restrict__ in, float* __restrict__ out, int rows) {
    int r = blockIdx.x * 256 + threadIdx.x;
    if (r >= rows) return;
    const float* p = in + (size_t)r * DD;
    float Bv[4];
#pragma unroll
    for (int blk = 0; blk < 4; blk++) {
        const float4* p4 = (const float4*)(p + blk * 128);
        float4 a = p4[0], b = p4[1];
        float a0 = __fmul_rn(a.x, a.x), a1 = __fmul_rn(a.y, a.y);
        float a2 = __fmul_rn(a.z, a.z), a3 = __fmul_rn(a.w, a.w);
        float a4 = __fmul_rn(b.x, b.x), a5 = __fmul_rn(b.y, b.y);
        float a6 = __fmul_rn(b.z, b.z), a7 = __fmul_rn(b.w, b.w);
#pragma unroll
        for (int t = 1; t < 16; t++) {
            a = p4[2 * t]; b = p4[2 * t + 1];
            a0 = __fadd_rn(a0, __fmul_rn(a.x, a.x)); a1 = __fadd_rn(a1, __fmul_rn(a.y, a.y));
            a2 = __fadd_rn(a2, __fmul_rn(a.z, a.z)); a3 = __fadd_rn(a3, __fmul_rn(a.w, a.w));
            a4 = __fadd_rn(a4, __fmul_rn(b.x, b.x)); a5 = __fadd_rn(a5, __fmul_rn(b.y, b.y));
            a6 = __fadd_rn(a6, __fmul_rn(b.z, b.z)); a7 = __fadd_rn(a7, __fmul_rn(b.w, b.w));
        }
        Bv[blk] = __fadd_rn(__fadd_rn(__fadd_rn(a0, a1), __fadd_rn(a2, a3)),
                            __fadd_rn(__fadd_rn(a4, a5), __fadd_rn(a6, a7)));
    }
    out[r] = __fadd_rn(__fadd_rn(Bv[0], Bv[1]), __fadd_rn(Bv[2], Bv[3]));
}

// bf16 MFMA pass1: dot[B,K] tile GEMM + per-row top-3/thread -> top-4/split
// shortlist on fine score w2[k] - 2*dot. bf16 dot error ~5e-6 << 1.3e-4 tie
// window; rerank (exact f32-chain) decides among the 16 captured candidates.
// LDS: linear-dest global_load_lds + inverse-XOR source + XOR ds_read (rule 21).
__global__ __launch_bounds__(256, 2)
void pass1_mfma_kernel(const u16* __restrict__ Zb, const u16* __restrict__ Wb,
                       const float* __restrict__ w2, int* __restrict__ ti) {
    __shared__ u64 smem64[4224];          // 33792 B: A-tile 16K | B-tile 16K; merge reuses
    char* smem = (char*)smem64;

    // XCD-chunked swizzle: 1024 wgs / 8 XCDs = 128 per XCD; the 4 splits of a
    // row-block land on the same XCD (shared A-panel in L2).
    int bx = blockIdx.x;
    int bxs = (bx & 7) * 128 + (bx >> 3);
    int sp = bxs & 3;
    int rb = bxs >> 2;
    int row0 = rb * BMM, col0 = sp * KRANGE;

    int tid = threadIdx.x;
    int lane = tid & 63, wid = tid >> 6;
    int wr = wid >> 1, wc = wid & 1;          // wave's 64x64 quadrant
    int l15 = lane & 15, g = lane >> 4, l7 = lane & 7;
    int srow = lane >> 3;                     // staging: row within 8-row group
    int schunk = l7 ^ srow;                   // staging: global chunk for this lane

    u64 K3[16][3];
#pragma unroll
    for (int s = 0; s < 16; s++) { K3[s][0] = ~0ull; K3[s][1] = ~0ull; K3[s][2] = ~0ull; }

    for (int ct = 0; ct < NCT; ++ct) {
        int kc0 = col0 + ct * BNN;
        f32x4 acc[4][4];
#pragma unroll
        for (int m = 0; m < 4; m++)
#pragma unroll
            for (int n = 0; n < 4; n++) acc[m][n] = (f32x4)(0.0f);

        for (int d0 = 0; d0 < DD; d0 += 64) {
            __syncthreads();   // readers done with LDS
            // stage A[128][64] + B[128][64] bf16; wave handles 4 issues each
#pragma unroll
            for (int ii = 0; ii < 4; ii++) {
                int issue = wid * 4 + ii;
                int trow = issue * 8 + srow;
                const char* gpA = (const char*)Zb +
                    (((size_t)(row0 + trow) * DD) + d0 + schunk * 8) * 2;
                __builtin_amdgcn_global_load_lds((const void*)gpA,
                    (void*)(smem + issue * 1024), 16, 0, 0);
                const char* gpB = (const char*)Wb +
                    (((size_t)(kc0 + trow) * DD) + d0 + schunk * 8) * 2;
                __builtin_amdgcn_global_load_lds((const void*)gpB,
                    (void*)(smem + 16384 + issue * 1024), 16, 0, 0);
            }
            __syncthreads();   // stages visible (compiler drains vmcnt at barrier)
#pragma unroll
            for (int ks = 0; ks < 2; ks++) {
                int sA = ((ks * 4 + g) ^ l7) << 4;   // swizzled 16B chunk slot
                bf16x8 aF[4], bF[4];
#pragma unroll
                for (int m = 0; m < 4; m++) {
                    int ar = wr * 64 + m * 16 + l15;
                    aF[m] = *(const bf16x8*)(smem + ar * 128 + sA);
                }
#pragma unroll
                for (int n = 0; n < 4; n++) {
                    int br = wc * 64 + n * 16 + l15;
                    bF[n] = *(const bf16x8*)(smem + 16384 + br * 128 + sA);
                }
#pragma unroll
                for (int m = 0; m < 4; m++)
#pragma unroll
                    for (int n = 0; n < 4; n++)
                        acc[m][n] = __builtin_amdgcn_mfma_f32_16x16x32_bf16(
                            aF[m], bF[n], acc[m][n], 0, 0, 0);
            }
        }
        // epilogue: shortlist insert. C/D map: col = lane&15, row = g*4 + reg.
#pragma unroll
        for (int n = 0; n < 4; n++) {
            int col = kc0 + wc * 64 + n * 16 + l15;
            float w2c = w2[col];
#pragma unroll
            for (int m = 0; m < 4; m++) {
#pragma unroll
                for (int r = 0; r < 4; r++) {
                    float e = fmaf(-2.0f, acc[m][n][r], w2c);
                    u64 x = sortable_pack(e, col);
                    int s = m * 4 + r;
                    if (x < K3[s][2]) {
                        u64 t1 = umax64(K3[s][0], x); K3[s][0] = umin64(K3[s][0], x);
                        u64 t2 = umax64(K3[s][1], t1); K3[s][1] = umin64(K3[s][1], t1);
                        K3[s][2] = umin64(K3[s][2], t2);
                    }
                }
            }
        }
    }

    // merge: 4 phases x 32 rows; per row 32 threads x 3 entries -> top-4
    u64* mb = smem64;   // [32][97] u64 = 24832 B
    for (int ph = 0; ph < 4; ph++) {
        __syncthreads();
        if (wr == (ph >> 1)) {
            int m0 = (ph & 1) * 2;
#pragma unroll
            for (int mi = 0; mi < 2; mi++) {
#pragma unroll
                for (int r = 0; r < 4; r++) {
                    int rip = mi * 16 + g * 4 + r;     // row in phase
                    int slot = wc * 16 + l15;
                    int s = (m0 + mi) * 4 + r;
                    u64* dst = &mb[rip * 97 + slot * 3];
                    dst[0] = K3[s][0]; dst[1] = K3[s][1]; dst[2] = K3[s][2];
                }
            }
        }
        __syncthreads();
        if (tid < 32) {
            u64 k0 = ~0ull, k1 = ~0ull, k2 = ~0ull, k3 = ~0ull;
            for (int e2 = 0; e2 < 96; e2++) {
                u64 x = mb[tid * 97 + e2];
                if (x < k3) {
                    u64 t1 = umax64(k0, x); k0 = umin64(k0, x);
                    u64 t2 = umax64(k1, t1); k1 = umin64(k1, t1);
                    u64 t3 = umax64(k2, t2); k2 = umin64(k2, t2);
                    k3 = umin64(k3, t3);
                }
            }
            int row = row0 + ph * 32 + tid;
            size_t o = ((size_t)sp * BB + row) * TOPS;
            ti[o + 0] = (int)(u32)k0;
            ti[o + 1] = (int)(u32)k1;
            ti[o + 2] = (int)(u32)k2;
            ti[o + 3] = (int)(u32)k3;
        }
    }
}

// One wave per row: emulate the reference f32 distance chain over 16 candidates.
// dist = fl32( fl32( zz - 2*fl32(dot_f64) ) + w2 ), argmin with lowest-index ties.
__global__ __launch_bounds__(256)
void rerank_kernel(const float* __restrict__ Z, const float* __restrict__ W,
                   const int* __restrict__ ti, const float* __restrict__ zzv,
                   const float* __restrict__ w2,
                   float* __restrict__ outq, float* __restrict__ outi,
                   float* __restrict__ counts, float* __restrict__ seg,
                   double* __restrict__ loss_acc) {
    int row = (blockIdx.x * blockDim.x + threadIdx.x) >> 6;
    int lane = threadIdx.x & 63;
    if (row >= BB) return;
    const float* zp = Z + (size_t)row * DD;
    float zf[8];
#pragma unroll
    for (int j = 0; j < 8; j++) zf[j] = zp[lane + j * 64];
    float zz = zzv[row];

    u64 best = ~0ull;
    for (int c = 0; c < NSPLIT * TOPS; c++) {
        int ix = ti[((size_t)(c >> 2) * BB + row) * TOPS + (c & 3)];
        const float* wp = W + (size_t)ix * DD;
        double dot = 0.0;
#pragma unroll
        for (int j = 0; j < 8; j++)
            dot = fma((double)zf[j], (double)wp[lane + j * 64], dot);
#pragma unroll
        for (int o = 32; o; o >>= 1) dot += __shfl_down(dot, o, 64);
        float E = (float)dot;
        E = __shfl(E, 0, 64);
        float dist = __fadd_rn(__fadd_rn(zz, __fmul_rn(-2.0f, E)), w2[ix]);
        u64 x = sortable_pack(dist, ix);
        best = umin64(best, x);
    }
    int besti = (int)(u32)best;

    if (!lane) { outi[row] = (float)besti; atomicAdd(&counts[besti], 1.0f); }
    const float* wp = W + (size_t)besti * DD;
    double ls = 0.0;
#pragma unroll
    for (int j = 0; j < 8; j++) {
        float q = wp[lane + j * 64];
        // quantized_st = fl(z + fl(q - z)) to match the reference bit pattern
        outq[(size_t)row * DD + lane + j * 64] = __fadd_rn(zf[j], __fsub_rn(q, zf[j]));
        float d = __fsub_rn(zf[j], q);
        ls = fma((double)d, (double)d, ls);
        atomicAdd(&seg[(size_t)besti * DD + lane + j * 64], zf[j]);
    }
#pragma unroll
    for (int o = 32; o; o >>= 1) ls += __shfl_down(ls, o, 64);
    if (!lane) atomicAdd(loss_acc, ls);
}

// single block: new_ema_cluster_size, n, cs_norm, losses, perplexity
__global__ void finalize_kernel(const float* __restrict__ ema_cs,
                                const float* __restrict__ counts,
                                const double* __restrict__ loss_acc,
                                float* __restrict__ out_ncs,
                                float* __restrict__ out_scal,
                                float* __restrict__ csnorm) {
    __shared__ double sn[256], sh[256];
    int tid = threadIdx.x;
    double nl = 0.0, hl = 0.0;
    for (int k = tid; k < KC; k += 256) {
        float c = counts[k];
        float ncs = 0.99f * ema_cs[k] + 0.01f * c;
        out_ncs[k] = ncs;
        nl += (double)ncs;
        double p = (double)c * (1.0 / (double)BB);
        hl += p * log(p + 1e-10);
    }
    sn[tid] = nl; sh[tid] = hl; __syncthreads();
    for (int s = 128; s; s >>= 1) {
        if (tid < s) { sn[tid] += sn[tid + s]; sh[tid] += sh[tid + s]; }
        __syncthreads();
    }
    if (!tid) {
        double L = loss_acc[0] * (1.0 / ((double)BB * DD));
        out_scal[0] = (float)L;              // commitment_loss
        out_scal[1] = (float)L;              // codebook_loss (same value)
        out_scal[2] = (float)(L + 0.25 * L); // vq_loss
        out_scal[3] = (float)exp(-sh[0]);    // perplexity
    }
    double n = sn[0];
    for (int k = tid; k < KC; k += 256) {
        double ncs = (double)out_ncs[k];
        csnorm[k] = (float)((ncs + 1e-5) / (n + (double)KC * 1e-5) * n);
    }
}

// elementwise: new_ema_embedding_sum and new_codebook
__global__ __launch_bounds__(256)
void ema_kernel(const float* __restrict__ ema_sum, const float* __restrict__ seg,
                const float* __restrict__ csnorm,
                float* __restrict__ out_ns, float* __restrict__ out_cb) {
    int i = blockIdx.x * 256 + threadIdx.x;
    if (i >= KC * DD / 4) return;
    int k = i >> 7;   // DD/4 = 128 float4 per row
    float4 es = ((const float4*)ema_sum)[i];
    float4 sg = ((const float4*)seg)[i];
    float4 ns;
    ns.x = 0.99f * es.x + 0.01f * sg.x;
    ns.y = 0.99f * es.y + 0.01f * sg.y;
    ns.z = 0.99f * es.z + 0.01f * sg.z;
    ns.w = 0.99f * es.w + 0.01f * sg.w;
    ((float4*)out_ns)[i] = ns;
    float cn = csnorm[k];
    float4 cb; cb.x = ns.x / cn; cb.y = ns.y / cn; cb.z = ns.z / cn; cb.w = ns.w / cn;
    ((float4*)out_cb)[i] = cb;
}

extern "C" void kernel_launch(void* const* d_in, const int* in_sizes, int n_in,
                              void* d_out, int out_size, void* d_ws, size_t ws_size,
                              hipStream_t stream) {
    (void)in_sizes; (void)n_in; (void)out_size; (void)ws_size;
    const float* Z       = (const float*)d_in[0];
    const float* W       = (const float*)d_in[1];
    const float* ema_cs  = (const float*)d_in[2];
    const float* ema_sum = (const float*)d_in[3];
    float* out = (float*)d_out;
    char* ws = (char*)d_ws;

    float*  seg  = (float*)(ws + WS_SEG);
    float*  cnt  = (float*)(ws + WS_CNT);
    double* loss = (double*)(ws + WS_LOSS);
    float*  w2   = (float*)(ws + WS_W2);
    float*  zz   = (float*)(ws + WS_ZZ);
    int*    ti   = (int*)(ws + WS_TI);
    float*  csn  = (float*)(ws + WS_CSN);
    u16*    Wb   = (u16*)(ws + WS_WB);
    u16*    Zb   = (u16*)(out + OQ);   // scratch in outq region; rerank overwrites after

    hipMemsetAsync(ws, 0, ZERO_BYTES, stream);   // seg + counts + loss
    np_sqnorm_kernel<<<KC / 256, 256, 0, stream>>>(W, w2, KC);
    np_sqnorm_kernel<<<BB / 256, 256, 0, stream>>>(Z, zz, BB);
    cvt_kernel<<<(BB * DD / 8) / 256, 256, 0, stream>>>(Z, Zb, BB * DD / 8);
    cvt_kernel<<<(KC * DD / 8) / 256, 256, 0, stream>>>(W, Wb, KC * DD / 8);
    pass1_mfma_kernel<<<(BB / BMM) * NSPLIT, 256, 0, stream>>>(Zb, Wb, w2, ti);
    rerank_kernel<<<BB / 4, 256, 0, stream>>>(Z, W, ti, zz, w2, out + OQ, out + OI, cnt, seg, loss);
    finalize_kernel<<<1, 256, 0, stream>>>(ema_cs, cnt, loss, out + ONC, out + OS, csn);
    ema_kernel<<<KC * DD / 4 / 256, 256, 0, stream>>>(ema_sum, seg, csn, out + ONS, out + OCB);
}

// Round 8
// 1489.718 us; speedup vs baseline: 3.1981x; 1.0790x over previous
//
#include <hip/hip_runtime.h>
#include <math.h>

typedef unsigned long long u64;
typedef unsigned int u32;
typedef unsigned short u16;
typedef __attribute__((ext_vector_type(8))) short bf16x8;
typedef __attribute__((ext_vector_type(8))) u16  u16x8;
typedef __attribute__((ext_vector_type(4))) float f32x4;

// Problem constants
#define KC 8192     // num_embeddings
#define DD 512      // embedding_dim
#define BB 32768    // batch
// Pass1 tiling
#define NSPLIT 4
#define KRANGE (KC / NSPLIT)   // 2048
#define BMM 128                // row tile
#define BNN 128                // col tile
#define NCT (KRANGE / BNN)     // 16 col-tiles per split
#define TOPS 4                 // candidates kept per (row, split)
#define MARGIN 6e-4f           // bf16-score vs f32-chain discrepancy bound (~4x slack)

// ---------------- workspace layout (bytes) ----------------
#define WS_SEG   0ull                                     // f32 [KC*DD] segment sum (zeroed)
#define WS_CNT   (WS_SEG + (size_t)KC * DD * 4)           // f32 [KC] counts (zeroed)
#define WS_LOSS  (WS_CNT + (size_t)KC * 4)                // f64 [1] loss accum (zeroed)
#define WS_W2    (WS_LOSS + 8)                            // f32 [KC] ||w||^2 (numpy-exact)
#define WS_ZZ    (WS_W2 + (size_t)KC * 4)                 // f32 [BB] ||z||^2 (numpy-exact)
#define WS_TI    (WS_ZZ + (size_t)BB * 4)                 // u64 [NSPLIT][BB][TOPS] (score,idx)
#define WS_CSN   (WS_TI + (size_t)NSPLIT * BB * TOPS * 8) // f32 [KC] cs_norm
#define WS_WB    (WS_CSN + (size_t)KC * 4)                // u16 [KC*DD] bf16 codebook
#define ZERO_BYTES (WS_LOSS + 8)

// ---------------- output layout (f32 elements) ----------------
#define OQ  0ull                        // quantized_st [BB*DD]
#define OI  ((size_t)BB * DD)           // indices as float [BB]
#define OS  (OI + BB)                   // commitment, codebook, vq, perplexity [4]
#define ONC (OS + 4)                    // new_ema_cluster_size [KC]
#define ONS (ONC + KC)                  // new_ema_embedding_sum [KC*DD]
#define OCB (ONS + (size_t)KC * DD)     // new_codebook [KC*DD]

__device__ __forceinline__ u64 sortable_pack(float e, int col) {
    u32 s = __float_as_uint(e);
    s = (s & 0x80000000u) ? ~s : (s | 0x80000000u);
    return ((u64)s << 32) | (u32)col;
}
__device__ __forceinline__ float sortable_unpack_val(u64 x) {
    u32 s = (u32)(x >> 32);
    u32 u = (s & 0x80000000u) ? (s & 0x7fffffffu) : ~s;
    return __uint_as_float(u);
}
__device__ __forceinline__ u64 umin64(u64 a, u64 b) { return a < b ? a : b; }
__device__ __forceinline__ u64 umax64(u64 a, u64 b) { return a > b ? a : b; }
__device__ __forceinline__ u16 f2bf(float f) {   // RNE f32 -> bf16
    u32 u = __float_as_uint(f);
    u32 r = u + 0x7FFFu + ((u >> 16) & 1u);
    return (u16)(r >> 16);
}

// f32 -> bf16 bulk convert, 8 elements/thread
__global__ __launch_bounds__(256)
void cvt_kernel(const float* __restrict__ in, u16* __restrict__ out, int n8) {
    int i = blockIdx.x * 256 + threadIdx.x;
    if (i >= n8) return;
    float4 a = ((const float4*)in)[2 * i];
    float4 b = ((const float4*)in)[2 * i + 1];
    u16x8 r = { f2bf(a.x), f2bf(a.y), f2bf(a.z), f2bf(a.w),
                f2bf(b.x), f2bf(b.y), f2bf(b.z), f2bf(b.w) };
    ((u16x8*)out)[i] = r;
}

// numpy-exact pairwise sum of squares, wave-parallel: lane l<32 owns chain
// (blk=l>>3, acc=l&7) of the n=512 pairwise tree; xor-butterfly 1,2,4 combines
// the 8 accumulators (exact tree since fl-add commutes), 8,16 combine blocks.
// 2 rows per wave (upper half lanes = row+1).
__global__ __launch_bounds__(256)
void np_sqnorm_kernel(const float* __restrict__ in, float* __restrict__ out, int rows) {
    int wv = (blockIdx.x * 256 + threadIdx.x) >> 6;
    int lane = threadIdx.x & 63;
    int r = wv * 2 + (lane >> 5);
    if (r >= rows) return;
    int l = lane & 31, b = l >> 3, a = l & 7;
    const float* p = in + (size_t)r * DD + b * 128 + a;
    float s = 0.0f;
#pragma unroll
    for (int t = 0; t < 16; t++) { float v = p[t * 8]; s = __fadd_rn(s, __fmul_rn(v, v)); }
    s = __fadd_rn(s, __shfl_xor(s, 1, 64));
    s = __fadd_rn(s, __shfl_xor(s, 2, 64));
    s = __fadd_rn(s, __shfl_xor(s, 4, 64));
    s = __fadd_rn(s, __shfl_xor(s, 8, 64));
    s = __fadd_rn(s, __shfl_xor(s, 16, 64));
    if (l == 0) out[r] = s;
}

// bf16 MFMA pass1: per-row top-3/thread -> top-4/split (score,idx) u64 shortlist
// on fine score w2[k] - 2*dot. XCD-pair owns one split (2MB Wb slice, L2-fits).
__global__ __launch_bounds__(256, 2)
void pass1_mfma_kernel(const u16* __restrict__ Zb, const u16* __restrict__ Wb,
                       const float* __restrict__ w2, u64* __restrict__ ti) {
    __shared__ u64 smem64[4224];          // 33792 B: A-tile 16K | B-tile 16K; merge reuses
    char* smem = (char*)smem64;

    // L2-residency swizzle: xcd = bx&7 (round-robin dispatch); each XCD PAIR
    // owns one split (its 2 MB Wb slice stays L2-resident); rb walks rows.
    int bx = blockIdx.x;
    int xcd = bx & 7, slot = bx >> 3;
    int sp = xcd >> 1;
    int rb = (xcd & 1) * 128 + slot;
    int row0 = rb * BMM, col0 = sp * KRANGE;

    int tid = threadIdx.x;
    int lane = tid & 63, wid = tid >> 6;
    int wr = wid >> 1, wc = wid & 1;          // wave's 64x64 quadrant
    int l15 = lane & 15, g = lane >> 4, l7 = lane & 7;
    int srow = lane >> 3;                     // staging: row within 8-row group
    int schunk = l7 ^ srow;                   // staging: global chunk for this lane

    u64 K3[16][3];
#pragma unroll
    for (int s = 0; s < 16; s++) { K3[s][0] = ~0ull; K3[s][1] = ~0ull; K3[s][2] = ~0ull; }

    for (int ct = 0; ct < NCT; ++ct) {
        int kc0 = col0 + ct * BNN;
        f32x4 acc[4][4];
#pragma unroll
        for (int m = 0; m < 4; m++)
#pragma unroll
            for (int n = 0; n < 4; n++) acc[m][n] = (f32x4)(0.0f);

        for (int d0 = 0; d0 < DD; d0 += 64) {
            __syncthreads();   // readers done with LDS
#pragma unroll
            for (int ii = 0; ii < 4; ii++) {
                int issue = wid * 4 + ii;
                int trow = issue * 8 + srow;
                const char* gpA = (const char*)Zb +
                    (((size_t)(row0 + trow) * DD) + d0 + schunk * 8) * 2;
                __builtin_amdgcn_global_load_lds((const void*)gpA,
                    (void*)(smem + issue * 1024), 16, 0, 0);
                const char* gpB = (const char*)Wb +
                    (((size_t)(kc0 + trow) * DD) + d0 + schunk * 8) * 2;
                __builtin_amdgcn_global_load_lds((const void*)gpB,
                    (void*)(smem + 16384 + issue * 1024), 16, 0, 0);
            }
            __syncthreads();   // stages visible
#pragma unroll
            for (int ks = 0; ks < 2; ks++) {
                int sA = ((ks * 4 + g) ^ l7) << 4;   // swizzled 16B chunk slot
                bf16x8 aF[4], bF[4];
#pragma unroll
                for (int m = 0; m < 4; m++) {
                    int ar = wr * 64 + m * 16 + l15;
                    aF[m] = *(const bf16x8*)(smem + ar * 128 + sA);
                }
#pragma unroll
                for (int n = 0; n < 4; n++) {
                    int br = wc * 64 + n * 16 + l15;
                    bF[n] = *(const bf16x8*)(smem + 16384 + br * 128 + sA);
                }
#pragma unroll
                for (int m = 0; m < 4; m++)
#pragma unroll
                    for (int n = 0; n < 4; n++)
                        acc[m][n] = __builtin_amdgcn_mfma_f32_16x16x32_bf16(
                            aF[m], bF[n], acc[m][n], 0, 0, 0);
            }
        }
        // epilogue: shortlist insert. C/D map: col = lane&15, row = g*4 + reg.
#pragma unroll
        for (int n = 0; n < 4; n++) {
            int col = kc0 + wc * 64 + n * 16 + l15;
            float w2c = w2[col];
#pragma unroll
            for (int m = 0; m < 4; m++) {
#pragma unroll
                for (int r = 0; r < 4; r++) {
                    float e = fmaf(-2.0f, acc[m][n][r], w2c);
                    u64 x = sortable_pack(e, col);
                    int s = m * 4 + r;
                    if (x < K3[s][2]) {
                        u64 t1 = umax64(K3[s][0], x); K3[s][0] = umin64(K3[s][0], x);
                        u64 t2 = umax64(K3[s][1], t1); K3[s][1] = umin64(K3[s][1], t1);
                        K3[s][2] = umin64(K3[s][2], t2);
                    }
                }
            }
        }
    }

    // merge: 4 phases x 32 rows; per row 32 threads x 3 entries -> top-4 u64s
    u64* mb = smem64;   // [32][97] u64 = 24832 B
    for (int ph = 0; ph < 4; ph++) {
        __syncthreads();
        if (wr == (ph >> 1)) {
            int m0 = (ph & 1) * 2;
#pragma unroll
            for (int mi = 0; mi < 2; mi++) {
#pragma unroll
                for (int r = 0; r < 4; r++) {
                    int rip = mi * 16 + g * 4 + r;     // row in phase
                    int slot2 = wc * 16 + l15;
                    int s = (m0 + mi) * 4 + r;
                    u64* dst = &mb[rip * 97 + slot2 * 3];
                    dst[0] = K3[s][0]; dst[1] = K3[s][1]; dst[2] = K3[s][2];
                }
            }
        }
        __syncthreads();
        if (tid < 32) {
            u64 k0 = ~0ull, k1 = ~0ull, k2 = ~0ull, k3 = ~0ull;
            for (int e2 = 0; e2 < 96; e2++) {
                u64 x = mb[tid * 97 + e2];
                if (x < k3) {
                    u64 t1 = umax64(k0, x); k0 = umin64(k0, x);
                    u64 t2 = umax64(k1, t1); k1 = umin64(k1, t1);
                    u64 t3 = umax64(k2, t2); k2 = umin64(k2, t2);
                    k3 = umin64(k3, t3);
                }
            }
            int row = row0 + ph * 32 + tid;
            size_t o = ((size_t)sp * BB + row) * TOPS;
            ti[o + 0] = k0; ti[o + 1] = k1; ti[o + 2] = k2; ti[o + 3] = k3;
        }
    }
}

// One wave per row. Margin filter: only candidates with bf-score within MARGIN
// of the bf-min need the exact f32-chain (avg ~1.6/row). Chain:
// dist = fl32( fl32( zz - 2*fl32(dot_f64) ) + w2 ), argmin with lowest-index ties.
__global__ __launch_bounds__(256)
void rerank_kernel(const float* __restrict__ Z, const float* __restrict__ W,
                   const u64* __restrict__ ti, const float* __restrict__ zzv,
                   const float* __restrict__ w2,
                   float* __restrict__ outq, float* __restrict__ outi,
                   float* __restrict__ counts, float* __restrict__ seg,
                   double* __restrict__ loss_acc) {
    int row = (blockIdx.x * blockDim.x + threadIdx.x) >> 6;
    int lane = threadIdx.x & 63;
    if (row >= BB) return;
    const float* zp = Z + (size_t)row * DD;
    float zf[8];
#pragma unroll
    for (int j = 0; j < 8; j++) zf[j] = zp[lane + j * 64];
    float zz = zzv[row];

    // lanes 0..15 hold one candidate each
    u64 cand = 0;
    if (lane < 16) cand = ti[((size_t)(lane >> 2) * BB + row) * TOPS + (lane & 3)];
    float cv = sortable_unpack_val(cand);     // NaN for non-candidate lanes is fine
    u64 mn = (lane < 16) ? cand : ~0ull;
#pragma unroll
    for (int o = 32; o; o >>= 1) mn = umin64(mn, __shfl_xor(mn, o, 64));
    float vminf = sortable_unpack_val(mn);
    bool surv = (lane < 16) && (cv <= vminf + MARGIN);
    unsigned long long mask = __ballot(surv);

    u64 best = ~0ull;
    while (mask) {
        int c = (int)(__ffsll((long long)mask) - 1); mask &= mask - 1;
        u64 cu = __shfl(cand, c, 64);
        int ix = (int)(u32)cu;
        const float* wp = W + (size_t)ix * DD;
        double dot = 0.0;
#pragma unroll
        for (int j = 0; j < 8; j++)
            dot = fma((double)zf[j], (double)wp[lane + j * 64], dot);
#pragma unroll
        for (int o = 32; o; o >>= 1) dot += __shfl_down(dot, o, 64);
        float E = (float)dot;
        E = __shfl(E, 0, 64);
        float dist = __fadd_rn(__fadd_rn(zz, __fmul_rn(-2.0f, E)), w2[ix]);
        best = umin64(best, sortable_pack(dist, ix));
    }
    int besti = (int)(u32)best;

    if (!lane) { outi[row] = (float)besti; atomicAdd(&counts[besti], 1.0f); }
    const float* wp = W + (size_t)besti * DD;
    double ls = 0.0;
#pragma unroll
    for (int j = 0; j < 8; j++) {
        float q = wp[lane + j * 64];
        // quantized_st = fl(z + fl(q - z)) to match the reference bit pattern
        outq[(size_t)row * DD + lane + j * 64] = __fadd_rn(zf[j], __fsub_rn(q, zf[j]));
        float d = __fsub_rn(zf[j], q);
        ls = fma((double)d, (double)d, ls);
        atomicAdd(&seg[(size_t)besti * DD + lane + j * 64], zf[j]);
    }
#pragma unroll
    for (int o = 32; o; o >>= 1) ls += __shfl_down(ls, o, 64);
    if (!lane) atomicAdd(loss_acc, ls);
}

// single block: new_ema_cluster_size, n, cs_norm, losses, perplexity
__global__ void finalize_kernel(const float* __restrict__ ema_cs,
                                const float* __restrict__ counts,
                                const double* __restrict__ loss_acc,
                                float* __restrict__ out_ncs,
                                float* __restrict__ out_scal,
                                float* __restrict__ csnorm) {
    __shared__ double sn[256], sh[256];
    int tid = threadIdx.x;
    double nl = 0.0, hl = 0.0;
    for (int k = tid; k < KC; k += 256) {
        float c = counts[k];
        float ncs = 0.99f * ema_cs[k] + 0.01f * c;
        out_ncs[k] = ncs;
        nl += (double)ncs;
        double p = (double)c * (1.0 / (double)BB);
        hl += p * log(p + 1e-10);
    }
    sn[tid] = nl; sh[tid] = hl; __syncthreads();
    for (int s = 128; s; s >>= 1) {
        if (tid < s) { sn[tid] += sn[tid + s]; sh[tid] += sh[tid + s]; }
        __syncthreads();
    }
    if (!tid) {
        double L = loss_acc[0] * (1.0 / ((double)BB * DD));
        out_scal[0] = (float)L;              // commitment_loss
        out_scal[1] = (float)L;              // codebook_loss (same value)
        out_scal[2] = (float)(L + 0.25 * L); // vq_loss
        out_scal[3] = (float)exp(-sh[0]);    // perplexity
    }
    double n = sn[0];
    for (int k = tid; k < KC; k += 256) {
        double ncs = (double)out_ncs[k];
        csnorm[k] = (float)((ncs + 1e-5) / (n + (double)KC * 1e-5) * n);
    }
}

// elementwise: new_ema_embedding_sum and new_codebook
__global__ __launch_bounds__(256)
void ema_kernel(const float* __restrict__ ema_sum, const float* __restrict__ seg,
                const float* __restrict__ csnorm,
                float* __restrict__ out_ns, float* __restrict__ out_cb) {
    int i = blockIdx.x * 256 + threadIdx.x;
    if (i >= KC * DD / 4) return;
    int k = i >> 7;   // DD/4 = 128 float4 per row
    float4 es = ((const float4*)ema_sum)[i];
    float4 sg = ((const float4*)seg)[i];
    float4 ns;
    ns.x = 0.99f * es.x + 0.01f * sg.x;
    ns.y = 0.99f * es.y + 0.01f * sg.y;
    ns.z = 0.99f * es.z + 0.01f * sg.z;
    ns.w = 0.99f * es.w + 0.01f * sg.w;
    ((float4*)out_ns)[i] = ns;
    float cn = csnorm[k];
    float4 cb; cb.x = ns.x / cn; cb.y = ns.y / cn; cb.z = ns.z / cn; cb.w = ns.w / cn;
    ((float4*)out_cb)[i] = cb;
}

extern "C" void kernel_launch(void* const* d_in, const int* in_sizes, int n_in,
                              void* d_out, int out_size, void* d_ws, size_t ws_size,
                              hipStream_t stream) {
    (void)in_sizes; (void)n_in; (void)out_size; (void)ws_size;
    const float* Z       = (const float*)d_in[0];
    const float* W       = (const float*)d_in[1];
    const float* ema_cs  = (const float*)d_in[2];
    const float* ema_sum = (const float*)d_in[3];
    float* out = (float*)d_out;
    char* ws = (char*)d_ws;

    float*  seg  = (float*)(ws + WS_SEG);
    float*  cnt  = (float*)(ws + WS_CNT);
    double* loss = (double*)(ws + WS_LOSS);
    float*  w2   = (float*)(ws + WS_W2);
    float*  zz   = (float*)(ws + WS_ZZ);
    u64*    ti   = (u64*)(ws + WS_TI);
    float*  csn  = (float*)(ws + WS_CSN);
    u16*    Wb   = (u16*)(ws + WS_WB);
    u16*    Zb   = (u16*)(out + OQ);   // scratch in outq region; rerank overwrites after

    hipMemsetAsync(ws, 0, ZERO_BYTES, stream);   // seg + counts + loss
    np_sqnorm_kernel<<<KC / 8, 256, 0, stream>>>(W, w2, KC);      // 2 rows/wave, 8/block
    np_sqnorm_kernel<<<BB / 8, 256, 0, stream>>>(Z, zz, BB);
    cvt_kernel<<<(BB * DD / 8) / 256, 256, 0, stream>>>(Z, Zb, BB * DD / 8);
    cvt_kernel<<<(KC * DD / 8) / 256, 256, 0, stream>>>(W, Wb, KC * DD / 8);
    pass1_mfma_kernel<<<(BB / BMM) * NSPLIT, 256, 0, stream>>>(Zb, Wb, w2, ti);
    rerank_kernel<<<BB / 4, 256, 0, stream>>>(Z, W, ti, zz, w2, out + OQ, out + OI, cnt, seg, loss);
    finalize_kernel<<<1, 256, 0, stream>>>(ema_cs, cnt, loss, out + ONC, out + OS, csn);
    ema_kernel<<<KC * DD / 4 / 256, 256, 0, stream>>>(ema_sum, seg, csn, out + ONS, out + OCB);
}